// Round 6
// baseline (219.095 us; speedup 1.0000x reference)
//
#include <hip/hip_runtime.h>
#include <hip/hip_bf16.h>

// Problem constants (T, B, H, D_MODEL) = (4096, 16, 256, 256)
#define T_LEN 4096
#define BATCH 16
#define NH    256
#define DM    256
#define M_TOT (T_LEN * BATCH)   // 65536 rows for both GEMMs

typedef __hip_bfloat16 bf16;
typedef __attribute__((ext_vector_type(8))) short bf16x8;  // 8 bf16 = 4 VGPRs
typedef __attribute__((ext_vector_type(4))) float f32x4;

// manual RTNE f32->bf16 (bit-level) -- same rounding as __float2bfloat16
__device__ __forceinline__ unsigned short f2bf_bits(float f) {
    unsigned int u = __float_as_uint(f);
    return (unsigned short)((u + 0x7fffu + ((u >> 16) & 1u)) >> 16);
}

__device__ __forceinline__ bf16x8 pack8(f32x4 lo, f32x4 hi) {
    union { unsigned short s[8]; bf16x8 v; } u;
    #pragma unroll
    for (int j = 0; j < 4; ++j) {
        u.s[j]     = f2bf_bits(lo[j]);
        u.s[4 + j] = f2bf_bits(hi[j]);
    }
    return u.v;
}

// async global->LDS, 16 B per lane. LDS dest must be wave-uniform base;
// HW scatters lane i to base + i*16 (m97/m104 contract -> LDS stays linear;
// swizzled layouts are achieved by pre-swizzling the GLOBAL source, m173).
typedef const unsigned int __attribute__((address_space(1)))* gas_ptr;
typedef unsigned int __attribute__((address_space(3)))* las_ptr;
__device__ __forceinline__ void async16(const bf16* g, bf16* l) {
    __builtin_amdgcn_global_load_lds((gas_ptr)g, (las_ptr)l, 16, 0, 0);
}
__device__ __forceinline__ void async16f(const float* g, float* l) {
    __builtin_amdgcn_global_load_lds((gas_ptr)g, (las_ptr)l, 16, 0, 0);
}

// ---------------------------------------------------------------------------
// Prep weights (bf16, transposed, complex-interleaved) + lam (block 1024).
// WaT: (512 x 256) [n][k].  n=2h: B_re[h][k]*gam[h]; n=2h+1: B_im[h][k]*gam[h]
// WcT: (256 x 512) [d][k].  k=2h: C_re[d][h];        k=2h+1: -C_im[d][h]
// lam: [2*NH] re then im.
// ---------------------------------------------------------------------------
__global__ __launch_bounds__(256) void prep_w_kernel(
    const float* __restrict__ nu_log, const float* __restrict__ theta_log,
    const float* __restrict__ B_re, const float* __restrict__ B_im,
    const float* __restrict__ C_re, const float* __restrict__ C_im,
    bf16* __restrict__ WaT, bf16* __restrict__ WcT, float* __restrict__ lam)
{
    if (blockIdx.x == 1024) {   // lam block
        int h = threadIdx.x;
        float mod = expf(-expf(nu_log[h]));   // |Lam| in [e^-e, e^-1]
        float ang = expf(theta_log[h]);
        lam[h]      = mod * cosf(ang);
        lam[NH + h] = mod * sinf(ang);
        return;
    }
    int idx = blockIdx.x * 256 + threadIdx.x;   // covers 2 * 131072
    if (idx < 512 * 256) {
        int n = idx >> 8, k = idx & 255;
        int h = n >> 1;
        float mod = expf(-expf(nu_log[h]));
        float gam = sqrtf(fmaxf(1.0f - mod * mod, 1e-8f));
        float v = ((n & 1) == 0 ? B_re[h * DM + k] : B_im[h * DM + k]) * gam;
        WaT[idx] = __float2bfloat16(v);
    } else {
        int j = idx - 512 * 256;
        int d = j >> 9, k = j & 511;
        int h = k >> 1;
        float v = ((k & 1) == 0) ? C_re[d * NH + h] : -C_im[d * NH + h];
        WcT[j] = __float2bfloat16(v);
    }
}

// ---------------------------------------------------------------------------
// Stage A GEMM (cvt fused, double-buffered): Bu[m][n] = sum_k bf16(x[m][k])
// * WaT[n][k]. 128x128 tile, BK=32, 8 K-iters, 4 waves 2x2.
// T3 minimum 2-phase: STAGE(t+1 -> buf^1) issues BEFORE compute(t); ONE
// barrier per iter (its implicit vmcnt(0) drains the stage; reads of buf^1
// finished before the PREVIOUS barrier, so the overwrite is race-free).
// A staged as f32 (cvt at fragment read); 16B-slot XOR swizzles on the
// pre-swizzled GLOBAL source (m173): A rows 128B slot^=row&7, B rows 64B
// slot^=(row>>1)&3 (both r4/r5-verified). LDS 2*(16+8)=48KB -> 3 blocks/CU.
// ---------------------------------------------------------------------------
__global__ __launch_bounds__(256) void gemm_a_kernel(
    const float* __restrict__ X,   // x (M,256) f32
    const bf16* __restrict__ BT,   // WaT (512,256)
    bf16* __restrict__ Cb)         // Bu (M,512)
{
    __shared__ float sAf[2][128 * 32];  // 2 x 16 KB, f32, swizzled 128B rows
    __shared__ bf16  sB [2][128 * 32];  // 2 x  8 KB, swizzled 64B rows

    const int tid  = threadIdx.x;
    const int lane = tid & 63;
    const int wid  = tid >> 6;

    const int bid = blockIdx.x;          // 2048 blocks
    const int xcd = bid & 7;
    const int sl  = bid >> 3;
    const int nt  = sl & 3;              // 4 n-tiles
    const int mt  = xcd * 64 + (sl >> 2);
    const int m0  = mt * 128;
    const int n0  = nt * 128;

    const int tm  = (wid >> 1) * 64;
    const int tn  = (wid & 1) * 64;
    const int l15 = lane & 15;
    const int q   = lane >> 4;

    // A staging: 64 lanes = 8 rows x 8 16B-slots; 4 rounds = 32 rows/wave.
    const int r8 = lane >> 3, s8 = lane & 7;
    // B staging: 64 lanes = 16 rows x 4 16B-slots; 2 rounds = 32 rows/wave.
    const int r16 = lane >> 2, s4 = lane & 3;

    const float* gA = X  + (size_t)(m0 + wid * 32 + r8) * 256 + (s8 ^ r8) * 4;
    const bf16*  gB = BT + (size_t)(n0 + wid * 32 + r16) * 256
                         + (s4 ^ ((r16 >> 1) & 3)) * 8;
    const int lofA = wid * 32 * 32;      // wave-uniform LDS elem offsets
    const int lofB = wid * 32 * 32;

    f32x4 acc[4][4];
    #pragma unroll
    for (int i = 0; i < 4; ++i)
        #pragma unroll
        for (int j = 0; j < 4; ++j) acc[i][j] = (f32x4){0.f, 0.f, 0.f, 0.f};

    // prologue: stage k0=0 into buf 0
    #pragma unroll
    for (int rr = 0; rr < 4; ++rr)
        async16f(gA + (size_t)(rr * 8) * 256, sAf[0] + lofA + rr * 8 * 32);
    #pragma unroll
    for (int rr = 0; rr < 2; ++rr)
        async16(gB + (size_t)(rr * 16) * 256, sB[0] + lofB + rr * 16 * 32);
    __syncthreads();

    #pragma unroll
    for (int t = 0; t < 8; ++t) {
        const int cur = t & 1;
        if (t < 7) {                      // stage t+1 into the other buffer
            const int k1 = (t + 1) * 32;
            #pragma unroll
            for (int rr = 0; rr < 4; ++rr)
                async16f(gA + (size_t)(rr * 8) * 256 + k1,
                         sAf[cur ^ 1] + lofA + rr * 8 * 32);
            #pragma unroll
            for (int rr = 0; rr < 2; ++rr)
                async16(gB + (size_t)(rr * 16) * 256 + k1,
                        sB[cur ^ 1] + lofB + rr * 16 * 32);
        }

        const char* A_ = (const char*)sAf[cur];
        const char* B_ = (const char*)sB[cur];
        bf16x8 af[4], bfr[4];
        #pragma unroll
        for (int i = 0; i < 4; ++i) {
            int ra = tm + i * 16 + l15;
            f32x4 lo = *(const f32x4*)(A_ + (size_t)ra * 128 +
                                       (((2 * q)     ^ (ra & 7)) * 16));
            f32x4 hi = *(const f32x4*)(A_ + (size_t)ra * 128 +
                                       (((2 * q + 1) ^ (ra & 7)) * 16));
            af[i] = pack8(lo, hi);
            int rb = tn + i * 16 + l15;
            bfr[i] = *(const bf16x8*)(B_ + (size_t)rb * 64 +
                                      ((q ^ ((rb >> 1) & 3)) * 16));
        }
        #pragma unroll
        for (int i = 0; i < 4; ++i)
            #pragma unroll
            for (int j = 0; j < 4; ++j)
                acc[i][j] = __builtin_amdgcn_mfma_f32_16x16x32_bf16(
                    af[i], bfr[j], acc[i][j], 0, 0, 0);

        if (t < 7) __syncthreads();   // drains stage(t+1); guards buf reuse
    }

    // C/D layout: col=lane&15, row=q*4+reg (m89/m91-verified)
    #pragma unroll
    for (int j = 0; j < 4; ++j) {
        int col = n0 + tn + j * 16 + l15;
        #pragma unroll
        for (int i = 0; i < 4; ++i) {
            #pragma unroll
            for (int r = 0; r < 4; ++r) {
                int row = m0 + tm + i * 16 + q * 4 + r;
                Cb[(size_t)row * 512 + col] = __float2bfloat16(acc[i][j][r]);
            }
        }
    }
}

// ---------------------------------------------------------------------------
// Fused scan + stage C (r4 structure + epilogue-x register preload).
// Block = (2 batches, 32-t chunk): 1024 blocks x 512 threads (8 waves), M=64.
// Phase 1: 512 scan chains; halo 8; start flags via per-wave __ballot;
//   h -> sH with 16B-slot XOR swizzle. sB chunk k0=0 prefetched pre-scan.
//   The 32 epilogue x-values load into registers right after the vbuf
//   prologue: they retire during phases 1-2 (issue-order vmcnt retirement),
//   so the epilogue is store-only (previously a synchronous 64MB read burst
//   at 26% HBM util). Nontemporal out stores keep LLC for Bu/x.
// Phase 2: out[64x256] = sH @ WcT^T + D*x, K=512, BK=32 async16-staged sB
//   with 4-slot swizzle.
// LDS: sH 64 KB + sB 16 KB = 81920 B exactly -> 2 blocks/CU (16 waves/CU).
// ---------------------------------------------------------------------------
#define SC  32
#define HL  8
#define PF  8     // scan prefetch depth

__global__ __launch_bounds__(512, 4) void scan_gemmc_kernel(
    const bf16* __restrict__ Bu,     // (M,512)
    const bf16* __restrict__ WcT,    // (256,512)
    const float* __restrict__ lam,   // [2*NH]
    const int* __restrict__ starts,  // (T,B)
    const float* __restrict__ state_re, const float* __restrict__ state_im,
    const float* __restrict__ x,     // (M,256) f32
    const float* __restrict__ Dvec,  // (256,)
    float* __restrict__ out)         // (M,256) f32
{
    __shared__ bf16 sH[64 * 512];    // 65536 B, XOR-swizzled
    __shared__ bf16 sB[256 * 32];    // 16384 B, slot-swizzled

    const int tid = threadIdx.x;
    const int bg  = blockIdx.x & 7;          // batch pair
    const int c   = blockIdx.x >> 3;         // t-chunk
    const int b0  = bg * 2;
    const int t0  = c * SC;
    const int tstart = (c == 0) ? 0 : t0 - HL;
    const int nIter  = t0 + SC - tstart;     // 32 or 40 (both % PF == 0)

    const int bi = tid >> 8;                 // 0/1: which batch of the pair
    const int h  = tid & 255;                // complex head
    const int b  = b0 + bi;

    // Wave/epilogue geometry (needed early for the x preload).
    const int lane = tid & 63;
    const int w    = tid >> 6;               // 0..7
    const int wm   = w >> 2;                 // rows wm*32..+32
    const int wn   = w & 3;                  // cols wn*64..+64
    const int l15  = lane & 15;
    const int q    = lane >> 4;

    // Phase-2 staging pointers (wave-level), set up early so we can prefetch.
    const int rsub = lane >> 2;              // 0..15: row within 16-row group
    const int sp   = lane & 3;               // physical 16B slot
    const int qlog = sp ^ ((rsub >> 1) & 3); // logical q stored at this slot
    const bf16* gBs = WcT + (size_t)(w * 32 + rsub) * 512 + qlog * 8;
    bf16* lBs = sB + w * 32 * 32;            // wave-uniform LDS base

    // start-bit mask: every wave ballots its own batch (wave 0-3 -> b0,
    // wave 4-7 -> b0+1). No LDS, no barrier.
    unsigned long long mask;
    {
        int st = (lane < nIter) ? starts[(tstart + lane) * BATCH + b] : 0;
        mask = __ballot(st != 0);
    }

    // Prefetch sB chunk for k0=0: overlaps the entire phase-1 scan.
    async16(gBs,            lBs);
    async16(gBs + 16 * 512, lBs + 16 * 32);

    // ---- Phase 1: scan (thread = complex head of one batch) ----
    float lr = lam[h], li = lam[NH + h];
    float hre = 0.0f, him = 0.0f;
    if (c == 0) { hre = state_re[b * NH + h]; him = state_im[b * NH + h]; }

    const bf16* bp = Bu + ((size_t)tstart * BATCH + b) * 512 + 2 * h;
    const size_t tstride = (size_t)BATCH * 512;   // elems per t step

    unsigned int vbuf[PF];
    #pragma unroll
    for (int p = 0; p < PF; ++p)
        vbuf[p] = *(const unsigned int*)(bp + p * tstride);   // PF <= 32 <= nIter

    // Pin the vbuf prologue before the x preload (retire-order: waiting on a
    // vbuf load then never waits on x; x retires under phases 1-2).
    __builtin_amdgcn_sched_barrier(0);

    // Epilogue x preload: 32 scalar loads -> registers (static indexing).
    float xv[2][4][4];
    #pragma unroll
    for (int j = 0; j < 4; ++j) {
        int col = wn * 64 + j * 16 + l15;
        #pragma unroll
        for (int i = 0; i < 2; ++i) {
            #pragma unroll
            for (int r = 0; r < 4; ++r) {
                int a = wm * 32 + i * 16 + q * 4 + r;
                size_t m = (size_t)(t0 + (a >> 1)) * BATCH + b0 + (a & 1);
                xv[i][j][r] = x[m * 256 + col];
            }
        }
    }

    char* sHB = (char*)sH;
    const int skip = nIter - SC;   // halo iterations before t0
    for (int base = 0; base < nIter; base += PF) {
        #pragma unroll
        for (int p = 0; p < PF; ++p) {
            int it = base + p;
            unsigned int v = vbuf[p];
            int tp = it + PF;
            if (tp < nIter)
                vbuf[p] = *(const unsigned int*)(bp + (size_t)tp * tstride);
            float bre = __uint_as_float(v << 16);
            float bim = __uint_as_float(v & 0xffff0000u);
            int st = (int)((mask >> it) & 1ull);
            float nr = st ? bre : fmaf(lr, hre, fmaf(-li, him, bre));
            float ni = st ? bim : fmaf(lr, him, fmaf(li, hre, bim));
            hre = nr; him = ni;
            int tl = it - skip;
            if (tl >= 0) {
                int a = tl * 2 + bi;                  // GEMM A-row
                int slot = (h >> 2) ^ (a & 7);        // 16B-slot XOR swizzle
                unsigned int packed =
                    ((unsigned int)f2bf_bits(him) << 16) | f2bf_bits(hre);
                *(unsigned int*)(sHB + a * 1024 + slot * 16 + (h & 3) * 4) = packed;
            }
        }
    }
    __syncthreads();   // sH published; sB(k0=0) + x preload drained

    // ---- Phase 2: GEMM 64x256, K=512; A from swizzled sH, B staged in sB ----
    const int slotq = q ^ ((l15 >> 1) & 3);   // sB read slot (row-invariant)

    f32x4 acc[2][4];
    #pragma unroll
    for (int i = 0; i < 2; ++i)
        #pragma unroll
        for (int j = 0; j < 4; ++j) acc[i][j] = (f32x4){0.f, 0.f, 0.f, 0.f};

    for (int it = 0; it < 16; ++it) {
        const int k0 = it * 32;

        bf16x8 af[2], bfr[4];
        #pragma unroll
        for (int i = 0; i < 2; ++i) {
            int a = wm * 32 + i * 16 + l15;
            int slot = ((k0 >> 3) + q) ^ (a & 7);
            af[i] = *(const bf16x8*)(sHB + a * 1024 + slot * 16);
        }
        #pragma unroll
        for (int j = 0; j < 4; ++j)
            bfr[j] = *(const bf16x8*)&sB[(wn * 64 + j * 16 + l15) * 32 + slotq * 8];

        __syncthreads();   // all waves have read sB (own lgkm drained pre-bar)

        if (it < 15) {     // begin overwriting sB for k0+32; MFMA hides part
            async16(gBs + k0 + 32,            lBs);
            async16(gBs + 16 * 512 + k0 + 32, lBs + 16 * 32);
        }

        #pragma unroll
        for (int i = 0; i < 2; ++i)
            #pragma unroll
            for (int j = 0; j < 4; ++j)
                acc[i][j] = __builtin_amdgcn_mfma_f32_16x16x32_bf16(
                    af[i], bfr[j], acc[i][j], 0, 0, 0);

        if (it < 15) __syncthreads();   // stage(it+1) landed (implicit vmcnt 0)
    }

    // Epilogue: a = tl*2 + bi -> m = (t0+tl)*16 + b0 + bi; store-only now.
    #pragma unroll
    for (int j = 0; j < 4; ++j) {
        int col = wn * 64 + j * 16 + l15;
        float dv = Dvec[col];
        #pragma unroll
        for (int i = 0; i < 2; ++i) {
            #pragma unroll
            for (int r = 0; r < 4; ++r) {
                int a = wm * 32 + i * 16 + q * 4 + r;
                size_t m = (size_t)(t0 + (a >> 1)) * BATCH + b0 + (a & 1);
                __builtin_nontemporal_store(
                    acc[i][j][r] + dv * xv[i][j][r], &out[m * 256 + col]);
            }
        }
    }
}

// ---------------------------------------------------------------------------
// Launch. Workspace: lam 2KB | WaT 256KB | WcT 256KB | Bu 64MB (~65MB total).
// 3 kernels total.
// ---------------------------------------------------------------------------
extern "C" void kernel_launch(void* const* d_in, const int* in_sizes, int n_in,
                              void* d_out, int out_size, void* d_ws, size_t ws_size,
                              hipStream_t stream)
{
    const float* x         = (const float*)d_in[0];
    const int*   starts    = (const int*)d_in[1];
    const float* state_re  = (const float*)d_in[2];
    const float* state_im  = (const float*)d_in[3];
    const float* nu_log    = (const float*)d_in[4];
    const float* theta_log = (const float*)d_in[5];
    const float* B_re      = (const float*)d_in[6];
    const float* B_im      = (const float*)d_in[7];
    const float* C_re      = (const float*)d_in[8];
    const float* C_im      = (const float*)d_in[9];
    const float* Dvec      = (const float*)d_in[10];
    float* out = (float*)d_out;

    char* ws = (char*)d_ws;
    float* lam = (float*)ws;                            // 2*NH f32
    bf16*  WaT = (bf16*)(ws + 4096);                    // 512x256 bf16
    bf16*  WcT = (bf16*)(ws + 4096 + 512 * 256 * 2);    // 256x512 bf16
    bf16*  Bu  = (bf16*)(ws + (1 << 20));               // 65536x512 bf16 (64MB)

    // Prep weights + lam (block 1024): one launch.
    prep_w_kernel<<<1025, 256, 0, stream>>>(nu_log, theta_log,
                                            B_re, B_im, C_re, C_im,
                                            WaT, WcT, lam);

    // Stage A (cvt fused, dbuf): Bu = bf16(x) @ WaT^T  (M=65536,K=256,N=512).
    gemm_a_kernel<<<2048, 256, 0, stream>>>(x, WaT, Bu);

    // Fused scan + stage C: 1024 blocks = (chunk, batch-pair), 512 threads.
    scan_gemmc_kernel<<<(T_LEN / SC) * (BATCH / 2), 512, 0, stream>>>(
        Bu, WcT, lam, starts, state_re, state_im, x, Dvec, out);
}

// Round 8
// 218.489 us; speedup vs baseline: 1.0028x; 1.0028x over previous
//
#include <hip/hip_runtime.h>
#include <hip/hip_bf16.h>

// Problem constants (T, B, H, D_MODEL) = (4096, 16, 256, 256)
#define T_LEN 4096
#define BATCH 16
#define NH    256
#define DM    256
#define M_TOT (T_LEN * BATCH)   // 65536 rows for both GEMMs

typedef __hip_bfloat16 bf16;
typedef __attribute__((ext_vector_type(8))) short bf16x8;  // 8 bf16 = 4 VGPRs
typedef __attribute__((ext_vector_type(4))) float f32x4;

// manual RTNE f32->bf16 (bit-level) -- same rounding as __float2bfloat16
__device__ __forceinline__ unsigned short f2bf_bits(float f) {
    unsigned int u = __float_as_uint(f);
    return (unsigned short)((u + 0x7fffu + ((u >> 16) & 1u)) >> 16);
}

// pack8 via scalar casts: compiler fuses pairs into v_cvt_pk_bf16_f32
// (m240: scalar cast IS the fast path; manual bit-twiddle never fuses).
__device__ __forceinline__ bf16x8 pack8(f32x4 lo, f32x4 hi) {
    union { bf16 h[8]; bf16x8 v; } u;
    #pragma unroll
    for (int j = 0; j < 4; ++j) {
        u.h[j]     = __float2bfloat16(lo[j]);
        u.h[4 + j] = __float2bfloat16(hi[j]);
    }
    return u.v;
}

// async global->LDS, 16 B per lane. LDS dest must be wave-uniform base;
// HW scatters lane i to base + i*16 (m97/m104 contract -> LDS stays linear;
// swizzled layouts are achieved by pre-swizzling the GLOBAL source, m173).
typedef const unsigned int __attribute__((address_space(1)))* gas_ptr;
typedef unsigned int __attribute__((address_space(3)))* las_ptr;
__device__ __forceinline__ void async16(const bf16* g, bf16* l) {
    __builtin_amdgcn_global_load_lds((gas_ptr)g, (las_ptr)l, 16, 0, 0);
}
__device__ __forceinline__ void async16f(const float* g, float* l) {
    __builtin_amdgcn_global_load_lds((gas_ptr)g, (las_ptr)l, 16, 0, 0);
}

// ---------------------------------------------------------------------------
// Prep weights (bf16, transposed, complex-interleaved) + lam (block 1024).
// WaT: (512 x 256) [n][k].  n=2h: B_re[h][k]*gam[h]; n=2h+1: B_im[h][k]*gam[h]
// WcT: (256 x 512) [d][k].  k=2h: C_re[d][h];        k=2h+1: -C_im[d][h]
// lam: [2*NH] re then im.
// ---------------------------------------------------------------------------
__global__ __launch_bounds__(256) void prep_w_kernel(
    const float* __restrict__ nu_log, const float* __restrict__ theta_log,
    const float* __restrict__ B_re, const float* __restrict__ B_im,
    const float* __restrict__ C_re, const float* __restrict__ C_im,
    bf16* __restrict__ WaT, bf16* __restrict__ WcT, float* __restrict__ lam)
{
    if (blockIdx.x == 1024) {   // lam block
        int h = threadIdx.x;
        float mod = expf(-expf(nu_log[h]));   // |Lam| in [e^-e, e^-1]
        float ang = expf(theta_log[h]);
        lam[h]      = mod * cosf(ang);
        lam[NH + h] = mod * sinf(ang);
        return;
    }
    int idx = blockIdx.x * 256 + threadIdx.x;   // covers 2 * 131072
    if (idx < 512 * 256) {
        int n = idx >> 8, k = idx & 255;
        int h = n >> 1;
        float mod = expf(-expf(nu_log[h]));
        float gam = sqrtf(fmaxf(1.0f - mod * mod, 1e-8f));
        float v = ((n & 1) == 0 ? B_re[h * DM + k] : B_im[h * DM + k]) * gam;
        WaT[idx] = __float2bfloat16(v);
    } else {
        int j = idx - 512 * 256;
        int d = j >> 9, k = j & 511;
        int h = k >> 1;
        float v = ((k & 1) == 0) ? C_re[d * NH + h] : -C_im[d * NH + h];
        WcT[j] = __float2bfloat16(v);
    }
}

// ---------------------------------------------------------------------------
// Stage A GEMM (cvt fused, counted-vmcnt double-buffer):
// Bu[m][n] = sum_k bf16(x[m][k]) * WaT[n][k]. 128x128 tile, BK=32, 8 iters,
// 4 waves 2x2. T4 pattern (m218: counted-vs-drain0 = +38..73%):
//   iter t: STAGE(t+1 -> buf^1); s_waitcnt vmcnt(6)   [waits only stage(t),
//   issued one FULL iteration earlier]; s_barrier [all waves' stage(t)
//   landed]; ds_read+MFMA on buf; s_barrier [reads done -> next overwrite
//   safe]. No vmcnt(0) in the loop. Race-audit: barrier lockstep means no
//   wave issues STAGE into buf^1 before every wave passed the post-MFMA
//   barrier of the iteration that last read buf^1. Barrier counts are
//   wave-uniform (loop fully unrolled; t<7 is compile-time).
// A staged f32 (cvt at fragment read via hw cvt_pk); swizzles as r6
// (A rows 128B slot^=row&7; B rows 64B slot^=(row>>1)&3, m173 global-side).
// LDS 2*(16+8)=48KB -> 3 blocks/CU.
// ---------------------------------------------------------------------------
__global__ __launch_bounds__(256) void gemm_a_kernel(
    const float* __restrict__ X,   // x (M,256) f32
    const bf16* __restrict__ BT,   // WaT (512,256)
    bf16* __restrict__ Cb)         // Bu (M,512)
{
    __shared__ float sAf[2][128 * 32];  // 2 x 16 KB, f32, swizzled 128B rows
    __shared__ bf16  sB [2][128 * 32];  // 2 x  8 KB, swizzled 64B rows

    const int tid  = threadIdx.x;
    const int lane = tid & 63;
    const int wid  = tid >> 6;

    const int bid = blockIdx.x;          // 2048 blocks
    const int xcd = bid & 7;
    const int sl  = bid >> 3;
    const int nt  = sl & 3;              // 4 n-tiles
    const int mt  = xcd * 64 + (sl >> 2);
    const int m0  = mt * 128;
    const int n0  = nt * 128;

    const int tm  = (wid >> 1) * 64;
    const int tn  = (wid & 1) * 64;
    const int l15 = lane & 15;
    const int q   = lane >> 4;

    // A staging: 64 lanes = 8 rows x 8 16B-slots; 4 rounds = 32 rows/wave.
    const int r8 = lane >> 3, s8 = lane & 7;
    // B staging: 64 lanes = 16 rows x 4 16B-slots; 2 rounds = 32 rows/wave.
    const int r16 = lane >> 2, s4 = lane & 3;

    const float* gA = X  + (size_t)(m0 + wid * 32 + r8) * 256 + (s8 ^ r8) * 4;
    const bf16*  gB = BT + (size_t)(n0 + wid * 32 + r16) * 256
                         + (s4 ^ ((r16 >> 1) & 3)) * 8;
    const int lofA = wid * 32 * 32;      // wave-uniform LDS elem offsets
    const int lofB = wid * 32 * 32;

    f32x4 acc[4][4];
    #pragma unroll
    for (int i = 0; i < 4; ++i)
        #pragma unroll
        for (int j = 0; j < 4; ++j) acc[i][j] = (f32x4){0.f, 0.f, 0.f, 0.f};

    // prologue: stage k0=0 into buf 0 (6 loads/wave)
    #pragma unroll
    for (int rr = 0; rr < 4; ++rr)
        async16f(gA + (size_t)(rr * 8) * 256, sAf[0] + lofA + rr * 8 * 32);
    #pragma unroll
    for (int rr = 0; rr < 2; ++rr)
        async16(gB + (size_t)(rr * 16) * 256, sB[0] + lofB + rr * 16 * 32);

    #pragma unroll
    for (int t = 0; t < 8; ++t) {
        const int cur = t & 1;
        if (t < 7) {                      // stage t+1 into the other buffer
            const int k1 = (t + 1) * 32;
            #pragma unroll
            for (int rr = 0; rr < 4; ++rr)
                async16f(gA + (size_t)(rr * 8) * 256 + k1,
                         sAf[cur ^ 1] + lofA + rr * 8 * 32);
            #pragma unroll
            for (int rr = 0; rr < 2; ++rr)
                async16(gB + (size_t)(rr * 16) * 256 + k1,
                        sB[cur ^ 1] + lofB + rr * 16 * 32);
            // own stage(t) done: 6 newest outstanding = stage(t+1)
            asm volatile("s_waitcnt vmcnt(6)" ::: "memory");
        } else {
            asm volatile("s_waitcnt vmcnt(0)" ::: "memory");
        }
        __builtin_amdgcn_sched_barrier(0);   // nothing hoists above the wait
        __builtin_amdgcn_s_barrier();        // raw barrier: no vmcnt(0) drain

        const char* A_ = (const char*)sAf[cur];
        const char* B_ = (const char*)sB[cur];
        bf16x8 af[4], bfr[4];
        #pragma unroll
        for (int i = 0; i < 4; ++i) {
            int ra = tm + i * 16 + l15;
            f32x4 lo = *(const f32x4*)(A_ + (size_t)ra * 128 +
                                       (((2 * q)     ^ (ra & 7)) * 16));
            f32x4 hi = *(const f32x4*)(A_ + (size_t)ra * 128 +
                                       (((2 * q + 1) ^ (ra & 7)) * 16));
            af[i] = pack8(lo, hi);
            int rb = tn + i * 16 + l15;
            bfr[i] = *(const bf16x8*)(B_ + (size_t)rb * 64 +
                                      ((q ^ ((rb >> 1) & 3)) * 16));
        }
        #pragma unroll
        for (int i = 0; i < 4; ++i)
            #pragma unroll
            for (int j = 0; j < 4; ++j)
                acc[i][j] = __builtin_amdgcn_mfma_f32_16x16x32_bf16(
                    af[i], bfr[j], acc[i][j], 0, 0, 0);

        if (t < 7) __builtin_amdgcn_s_barrier();  // buf reads done -> reuse ok
    }

    // C/D layout: col=lane&15, row=q*4+reg (m89/m91-verified)
    #pragma unroll
    for (int j = 0; j < 4; ++j) {
        int col = n0 + tn + j * 16 + l15;
        #pragma unroll
        for (int i = 0; i < 4; ++i) {
            #pragma unroll
            for (int r = 0; r < 4; ++r) {
                int row = m0 + tm + i * 16 + q * 4 + r;
                Cb[(size_t)row * 512 + col] = __float2bfloat16(acc[i][j][r]);
            }
        }
    }
}

// ---------------------------------------------------------------------------
// Fused scan + stage C (r6 structure, verified ~63 us -- unchanged).
// Block = (2 batches, 32-t chunk): 1024 blocks x 512 threads (8 waves), M=64.
// Phase 1: 512 scan chains; halo 8; start flags via per-wave __ballot;
//   h -> sH with 16B-slot XOR swizzle. sB chunk k0=0 prefetched pre-scan.
//   Epilogue x-values preloaded to registers (retire under phases 1-2).
// Phase 2: out[64x256] = sH @ WcT^T + D*x, K=512, BK=32 async16-staged sB
//   with 4-slot swizzle. Nontemporal out stores.
// LDS: sH 64 KB + sB 16 KB = 81920 B exactly -> 2 blocks/CU (16 waves/CU).
// ---------------------------------------------------------------------------
#define SC  32
#define HL  8
#define PF  8     // scan prefetch depth

__global__ __launch_bounds__(512, 4) void scan_gemmc_kernel(
    const bf16* __restrict__ Bu,     // (M,512)
    const bf16* __restrict__ WcT,    // (256,512)
    const float* __restrict__ lam,   // [2*NH]
    const int* __restrict__ starts,  // (T,B)
    const float* __restrict__ state_re, const float* __restrict__ state_im,
    const float* __restrict__ x,     // (M,256) f32
    const float* __restrict__ Dvec,  // (256,)
    float* __restrict__ out)         // (M,256) f32
{
    __shared__ bf16 sH[64 * 512];    // 65536 B, XOR-swizzled
    __shared__ bf16 sB[256 * 32];    // 16384 B, slot-swizzled

    const int tid = threadIdx.x;
    const int bg  = blockIdx.x & 7;          // batch pair
    const int c   = blockIdx.x >> 3;         // t-chunk
    const int b0  = bg * 2;
    const int t0  = c * SC;
    const int tstart = (c == 0) ? 0 : t0 - HL;
    const int nIter  = t0 + SC - tstart;     // 32 or 40 (both % PF == 0)

    const int bi = tid >> 8;                 // 0/1: which batch of the pair
    const int h  = tid & 255;                // complex head
    const int b  = b0 + bi;

    // Wave/epilogue geometry (needed early for the x preload).
    const int lane = tid & 63;
    const int w    = tid >> 6;               // 0..7
    const int wm   = w >> 2;                 // rows wm*32..+32
    const int wn   = w & 3;                  // cols wn*64..+64
    const int l15  = lane & 15;
    const int q    = lane >> 4;

    // Phase-2 staging pointers (wave-level), set up early so we can prefetch.
    const int rsub = lane >> 2;              // 0..15: row within 16-row group
    const int sp   = lane & 3;               // physical 16B slot
    const int qlog = sp ^ ((rsub >> 1) & 3); // logical q stored at this slot
    const bf16* gBs = WcT + (size_t)(w * 32 + rsub) * 512 + qlog * 8;
    bf16* lBs = sB + w * 32 * 32;            // wave-uniform LDS base

    // start-bit mask: every wave ballots its own batch (wave 0-3 -> b0,
    // wave 4-7 -> b0+1). No LDS, no barrier.
    unsigned long long mask;
    {
        int st = (lane < nIter) ? starts[(tstart + lane) * BATCH + b] : 0;
        mask = __ballot(st != 0);
    }

    // Prefetch sB chunk for k0=0: overlaps the entire phase-1 scan.
    async16(gBs,            lBs);
    async16(gBs + 16 * 512, lBs + 16 * 32);

    // ---- Phase 1: scan (thread = complex head of one batch) ----
    float lr = lam[h], li = lam[NH + h];
    float hre = 0.0f, him = 0.0f;
    if (c == 0) { hre = state_re[b * NH + h]; him = state_im[b * NH + h]; }

    const bf16* bp = Bu + ((size_t)tstart * BATCH + b) * 512 + 2 * h;
    const size_t tstride = (size_t)BATCH * 512;   // elems per t step

    unsigned int vbuf[PF];
    #pragma unroll
    for (int p = 0; p < PF; ++p)
        vbuf[p] = *(const unsigned int*)(bp + p * tstride);   // PF <= 32 <= nIter

    // Pin the vbuf prologue before the x preload (retire-order: waiting on a
    // vbuf load then never waits on x; x retires under phases 1-2).
    __builtin_amdgcn_sched_barrier(0);

    // Epilogue x preload: 32 scalar loads -> registers (static indexing).
    float xv[2][4][4];
    #pragma unroll
    for (int j = 0; j < 4; ++j) {
        int col = wn * 64 + j * 16 + l15;
        #pragma unroll
        for (int i = 0; i < 2; ++i) {
            #pragma unroll
            for (int r = 0; r < 4; ++r) {
                int a = wm * 32 + i * 16 + q * 4 + r;
                size_t m = (size_t)(t0 + (a >> 1)) * BATCH + b0 + (a & 1);
                xv[i][j][r] = x[m * 256 + col];
            }
        }
    }

    char* sHB = (char*)sH;
    const int skip = nIter - SC;   // halo iterations before t0
    for (int base = 0; base < nIter; base += PF) {
        #pragma unroll
        for (int p = 0; p < PF; ++p) {
            int it = base + p;
            unsigned int v = vbuf[p];
            int tp = it + PF;
            if (tp < nIter)
                vbuf[p] = *(const unsigned int*)(bp + (size_t)tp * tstride);
            float bre = __uint_as_float(v << 16);
            float bim = __uint_as_float(v & 0xffff0000u);
            int st = (int)((mask >> it) & 1ull);
            float nr = st ? bre : fmaf(lr, hre, fmaf(-li, him, bre));
            float ni = st ? bim : fmaf(lr, him, fmaf(li, hre, bim));
            hre = nr; him = ni;
            int tl = it - skip;
            if (tl >= 0) {
                int a = tl * 2 + bi;                  // GEMM A-row
                int slot = (h >> 2) ^ (a & 7);        // 16B-slot XOR swizzle
                unsigned int packed =
                    ((unsigned int)f2bf_bits(him) << 16) | f2bf_bits(hre);
                *(unsigned int*)(sHB + a * 1024 + slot * 16 + (h & 3) * 4) = packed;
            }
        }
    }
    __syncthreads();   // sH published; sB(k0=0) + x preload drained

    // ---- Phase 2: GEMM 64x256, K=512; A from swizzled sH, B staged in sB ----
    const int slotq = q ^ ((l15 >> 1) & 3);   // sB read slot (row-invariant)

    f32x4 acc[2][4];
    #pragma unroll
    for (int i = 0; i < 2; ++i)
        #pragma unroll
        for (int j = 0; j < 4; ++j) acc[i][j] = (f32x4){0.f, 0.f, 0.f, 0.f};

    for (int it = 0; it < 16; ++it) {
        const int k0 = it * 32;

        bf16x8 af[2], bfr[4];
        #pragma unroll
        for (int i = 0; i < 2; ++i) {
            int a = wm * 32 + i * 16 + l15;
            int slot = ((k0 >> 3) + q) ^ (a & 7);
            af[i] = *(const bf16x8*)(sHB + a * 1024 + slot * 16);
        }
        #pragma unroll
        for (int j = 0; j < 4; ++j)
            bfr[j] = *(const bf16x8*)&sB[(wn * 64 + j * 16 + l15) * 32 + slotq * 8];

        __syncthreads();   // all waves have read sB (own lgkm drained pre-bar)

        if (it < 15) {     // begin overwriting sB for k0+32; MFMA hides part
            async16(gBs + k0 + 32,            lBs);
            async16(gBs + 16 * 512 + k0 + 32, lBs + 16 * 32);
        }

        #pragma unroll
        for (int i = 0; i < 2; ++i)
            #pragma unroll
            for (int j = 0; j < 4; ++j)
                acc[i][j] = __builtin_amdgcn_mfma_f32_16x16x32_bf16(
                    af[i], bfr[j], acc[i][j], 0, 0, 0);

        if (it < 15) __syncthreads();   // stage(it+1) landed (implicit vmcnt 0)
    }

    // Epilogue: a = tl*2 + bi -> m = (t0+tl)*16 + b0 + bi; store-only now.
    #pragma unroll
    for (int j = 0; j < 4; ++j) {
        int col = wn * 64 + j * 16 + l15;
        float dv = Dvec[col];
        #pragma unroll
        for (int i = 0; i < 2; ++i) {
            #pragma unroll
            for (int r = 0; r < 4; ++r) {
                int a = wm * 32 + i * 16 + q * 4 + r;
                size_t m = (size_t)(t0 + (a >> 1)) * BATCH + b0 + (a & 1);
                __builtin_nontemporal_store(
                    acc[i][j][r] + dv * xv[i][j][r], &out[m * 256 + col]);
            }
        }
    }
}

// ---------------------------------------------------------------------------
// Launch. Workspace: lam 2KB | WaT 256KB | WcT 256KB | Bu 64MB (~65MB total).
// 3 kernels total.
// ---------------------------------------------------------------------------
extern "C" void kernel_launch(void* const* d_in, const int* in_sizes, int n_in,
                              void* d_out, int out_size, void* d_ws, size_t ws_size,
                              hipStream_t stream)
{
    const float* x         = (const float*)d_in[0];
    const int*   starts    = (const int*)d_in[1];
    const float* state_re  = (const float*)d_in[2];
    const float* state_im  = (const float*)d_in[3];
    const float* nu_log    = (const float*)d_in[4];
    const float* theta_log = (const float*)d_in[5];
    const float* B_re      = (const float*)d_in[6];
    const float* B_im      = (const float*)d_in[7];
    const float* C_re      = (const float*)d_in[8];
    const float* C_im      = (const float*)d_in[9];
    const float* Dvec      = (const float*)d_in[10];
    float* out = (float*)d_out;

    char* ws = (char*)d_ws;
    float* lam = (float*)ws;                            // 2*NH f32
    bf16*  WaT = (bf16*)(ws + 4096);                    // 512x256 bf16
    bf16*  WcT = (bf16*)(ws + 4096 + 512 * 256 * 2);    // 256x512 bf16
    bf16*  Bu  = (bf16*)(ws + (1 << 20));               // 65536x512 bf16 (64MB)

    // Prep weights + lam (block 1024): one launch.
    prep_w_kernel<<<1025, 256, 0, stream>>>(nu_log, theta_log,
                                            B_re, B_im, C_re, C_im,
                                            WaT, WcT, lam);

    // Stage A (cvt fused, counted-vmcnt dbuf): Bu = bf16(x) @ WaT^T.
    gemm_a_kernel<<<2048, 256, 0, stream>>>(x, WaT, Bu);

    // Fused scan + stage C: 1024 blocks = (chunk, batch-pair), 512 threads.
    scan_gemmc_kernel<<<(T_LEN / SC) * (BATCH / 2), 512, 0, stream>>>(
        Bu, WcT, lam, starts, state_re, state_im, x, Dvec, out);
}